// Round 1
// baseline (109.854 us; speedup 1.0000x reference)
//
#include <hip/hip_runtime.h>
#include <hip/hip_bf16.h>

// QuantumKANLayer: S = [cos|sin features](32768x4096) @ W(4096x256), bf16 MFMA.
// BATCH=32768, N_IN=256, N_OUT=256, K=8 -> feature K-dim = 256*16 = 4096.

#define BM 128
#define BN 256
#define KSTEP 64           // 4 input columns per step (16 feats each)
#define NSTEPS 64          // 4096 / 64

typedef __attribute__((ext_vector_type(8))) short short8;
typedef __attribute__((ext_vector_type(4))) float f32x4;

typedef __attribute__((address_space(3))) void lds_void;
typedef const __attribute__((address_space(1))) void gbl_void;

static __device__ __forceinline__ unsigned short f2bf(float f) {
    union { float f; unsigned u; } v; v.f = f;
    unsigned r = v.u + 0x7fff + ((v.u >> 16) & 1);   // RNE
    return (unsigned short)(r >> 16);
}

// ---------------- kernel 1: pack W^T bf16 [256 j][4096 k], k = i*16 + kk ----
__global__ __launch_bounds__(256) void pack_w_kernel(
        const float* __restrict__ ca, const float* __restrict__ cb,
        unsigned short* __restrict__ wt) {
    int idx = blockIdx.x * 256 + threadIdx.x;        // 65536 = (j,i) pairs
    int j = idx >> 8, i = idx & 255;
    const float* pa = ca + (size_t)idx * 8;          // coef_a[j][i][0..7]
    const float* pb = cb + (size_t)idx * 8;
    alignas(16) unsigned short o[16];
#pragma unroll
    for (int k = 0; k < 8; ++k) o[k] = f2bf(pa[k]);
#pragma unroll
    for (int k = 0; k < 8; ++k) o[8 + k] = f2bf(pb[k]);
    unsigned short* dst = wt + (size_t)j * 4096 + (size_t)i * 16;
    *(uint4*)(dst)     = *(const uint4*)(&o[0]);
    *(uint4*)(dst + 8) = *(const uint4*)(&o[8]);
}

// ---------------- kernel 2: fused feature-gen + GEMM ----------------------
// LDS: A-feat tile 2 x [128 rows][64 k] bf16 (128B rows, 8 x 16B granules,
//      granule XOR-swizzled by row&7)                        = 32 KiB
//      B^T tile   2 x [256 cols][64 k] bf16 (same swizzle)   = 64 KiB
template<bool PACKED>
__global__ __launch_bounds__(512, 2) void kan_gemm(
        const float* __restrict__ x,
        const unsigned short* __restrict__ wt,
        const float* __restrict__ ca, const float* __restrict__ cb,
        float* __restrict__ out) {
    extern __shared__ char smem[];
    char* Alds = smem;              // 2 * 16384
    char* Blds = smem + 32768;      // 2 * 32768

    const int tid = threadIdx.x;
    const int l   = tid & 63;
    const int w   = tid >> 6;       // wave 0..7
    const int bm0 = blockIdx.x * BM;

    // feature-writer mapping: 512 threads = 128 rows x 4 i-columns
    const int frow = tid & 127;
    const int fi   = tid >> 7;       // 0..3
    const int fswz = frow & 7;

    // MFMA mapping: wave grid 2(M) x 4(N); each wave 64x64 output
    const int wm = w >> 2, wn = w & 3;
    const int q  = l >> 4;           // lane quarter
    const int c  = l & 15;
    const int lswz = l & 7;

    f32x4 acc[4][4];
#pragma unroll
    for (int a = 0; a < 4; ++a)
#pragma unroll
        for (int b = 0; b < 4; ++b)
#pragma unroll
            for (int r = 0; r < 4; ++r) acc[a][b][r] = 0.0f;

    // ---- B staging: 2048 granules of 16B per step (256 rows x 8 granules)
    auto stage_B = [&](int buf, int s) {
#pragma unroll
        for (int p = 0; p < 4; ++p) {
            const int gidb = (p * 8 + w) * 64;          // wave-uniform
            const int gid  = gidb + l;
            const int row  = gid >> 3;                  // output col j
            const int glog = (l & 7) ^ (row & 7);       // pre-swizzled source
            if (PACKED) {
                const char* src = (const char*)wt + (size_t)row * 8192
                                + (size_t)s * 128 + (size_t)glog * 16;
                char* dst = Blds + buf * 32768 + gidb * 16;   // linear dest
                __builtin_amdgcn_global_load_lds((gbl_void*)src, (lds_void*)dst,
                                                 16, 0, 0);
            } else {
                const int il = glog >> 1, h = glog & 1;
                const float* srcf = (h ? cb : ca)
                                  + ((size_t)row * 256 + (size_t)(s * 4 + il)) * 8;
                const float4* s4 = (const float4*)srcf;
                float4 v0 = s4[0], v1 = s4[1];
                alignas(16) unsigned short o[8];
                o[0] = f2bf(v0.x); o[1] = f2bf(v0.y);
                o[2] = f2bf(v0.z); o[3] = f2bf(v0.w);
                o[4] = f2bf(v1.x); o[5] = f2bf(v1.y);
                o[6] = f2bf(v1.z); o[7] = f2bf(v1.w);
                *(short8*)(Blds + buf * 32768 + (size_t)gid * 16) = *(short8*)o;
            }
        }
    };

    // ---- A staging: per thread one (row, i) pair -> 16 features -> 2 granules
    auto stage_A = [&](int buf, int s) {
        float xv = x[(size_t)(bm0 + frow) * 256 + (size_t)(s * 4 + fi)];
        float s1, c1;
        __sincosf(xv, &s1, &c1);
        alignas(16) unsigned short fc[8], fs[8];
        fc[0] = f2bf(c1); fs[0] = f2bf(s1);
        float ck = c1, sk = s1;
#pragma unroll
        for (int k = 1; k < 8; ++k) {
            float c2 = ck * c1 - sk * s1;
            float s2 = sk * c1 + ck * s1;
            ck = c2; sk = s2;
            fc[k] = f2bf(ck); fs[k] = f2bf(sk);
        }
        char* arow = Alds + buf * 16384 + frow * 128;
        *(short8*)(arow + (((fi * 2)     ^ fswz) * 16)) = *(short8*)fc;
        *(short8*)(arow + (((fi * 2 + 1) ^ fswz) * 16)) = *(short8*)fs;
    };

    // prologue
    stage_B(0, 0);
    stage_A(0, 0);
    __syncthreads();

#pragma unroll 1
    for (int s = 0; s < NSTEPS; ++s) {
        const int buf = s & 1;
        if (s + 1 < NSTEPS) {
            stage_B(buf ^ 1, s + 1);
            stage_A(buf ^ 1, s + 1);
        }
        const char* Ab = Alds + buf * 16384;
        const char* Bb = Blds + buf * 32768;
#pragma unroll
        for (int ks = 0; ks < 2; ++ks) {
            short8 af[4], bfv[4];
#pragma unroll
            for (int mi = 0; mi < 4; ++mi) {
                const int row = wm * 64 + mi * 16 + c;
                af[mi] = *(const short8*)(Ab + row * 128
                         + (((ks * 4 + q) ^ lswz) * 16));
            }
#pragma unroll
            for (int ni = 0; ni < 4; ++ni) {
                const int col = wn * 64 + ni * 16 + c;
                bfv[ni] = *(const short8*)(Bb + col * 128
                          + (((ks * 4 + q) ^ lswz) * 16));
            }
#pragma unroll
            for (int mi = 0; mi < 4; ++mi)
#pragma unroll
                for (int ni = 0; ni < 4; ++ni)
                    acc[mi][ni] = __builtin_amdgcn_mfma_f32_16x16x32_bf16(
                        af[mi], bfv[ni], acc[mi][ni], 0, 0, 0);
        }
        __syncthreads();
    }

    // epilogue: D row = q*4 + r, col = c within each 16x16 frag
#pragma unroll
    for (int mi = 0; mi < 4; ++mi)
#pragma unroll
        for (int ni = 0; ni < 4; ++ni) {
            const int col = wn * 64 + ni * 16 + c;
#pragma unroll
            for (int r = 0; r < 4; ++r) {
                const int row = bm0 + wm * 64 + mi * 16 + q * 4 + r;
                out[(size_t)row * 256 + col] = acc[mi][ni][r];
            }
        }
}

extern "C" void kernel_launch(void* const* d_in, const int* in_sizes, int n_in,
                              void* d_out, int out_size, void* d_ws, size_t ws_size,
                              hipStream_t stream) {
    const float* x  = (const float*)d_in[0];
    const float* ca = (const float*)d_in[1];
    const float* cb = (const float*)d_in[2];
    float* out = (float*)d_out;

    const size_t wt_bytes = (size_t)256 * 4096 * 2;   // 2 MiB bf16 W^T
    const size_t lds_bytes = 98304;                   // 32K A + 64K B

    if (ws_size >= wt_bytes) {
        unsigned short* wt = (unsigned short*)d_ws;
        pack_w_kernel<<<256, 256, 0, stream>>>(ca, cb, wt);
        kan_gemm<true><<<256, 512, lds_bytes, stream>>>(x, wt, ca, cb, out);
    } else {
        kan_gemm<false><<<256, 512, lds_bytes, stream>>>(x, nullptr, ca, cb, out);
    }
}

// Round 2
// 81.900 us; speedup vs baseline: 1.3413x; 1.3413x over previous
//
#include <hip/hip_runtime.h>
#include <hip/hip_bf16.h>

// QuantumKANLayer: S = [cos|sin features](32768x4096) @ W(4096x256), bf16 MFMA.
// R1: B-fragments direct from L2 (fragment-major repack, no B LDS),
//     BM=64 grid=512 (2 blocks/CU, 16 waves/CU), A-only LDS double buffer.

#define BM 64
#define KST 128          // k per step = 8 input columns
#define NST 32           // 4096 / 128

typedef __attribute__((ext_vector_type(8))) short short8;
typedef __attribute__((ext_vector_type(4))) float f32x4;

static __device__ __forceinline__ unsigned short f2bf(float f) {
    union { float f; unsigned u; } v; v.f = f;
    unsigned r = v.u + 0x7fff + ((v.u >> 16) & 1);   // RNE
    return (unsigned short)(r >> 16);
}

// ---- pack W^T into fragment-major bwt: block (t, cg) = 1 KiB, t=0..127 (32-k
// slices), cg=0..15 (16-col groups). Lane l=(q,c) 16B: j=cg*16+c, i=2t+(q>>1),
// octet = (q&1 ? coef_b : coef_a)[j][i][0..7] as bf16.
__global__ __launch_bounds__(256) void pack_w_kernel(
        const float* __restrict__ ca, const float* __restrict__ cb,
        unsigned short* __restrict__ wt) {
    int idx = blockIdx.x * 256 + threadIdx.x;   // 131072 lane-tasks
    int l = idx & 63;
    int q = l >> 4, c = l & 15;
    int cg = (idx >> 6) & 15;
    int t  = idx >> 10;
    int j = cg * 16 + c;
    int i = 2 * t + (q >> 1);
    const float* src = ((q & 1) ? cb : ca) + ((size_t)j * 256 + i) * 8;
    float4 v0 = ((const float4*)src)[0];
    float4 v1 = ((const float4*)src)[1];
    alignas(16) unsigned short o[8];
    o[0] = f2bf(v0.x); o[1] = f2bf(v0.y); o[2] = f2bf(v0.z); o[3] = f2bf(v0.w);
    o[4] = f2bf(v1.x); o[5] = f2bf(v1.y); o[6] = f2bf(v1.z); o[7] = f2bf(v1.w);
    *(short8*)(wt + (size_t)idx * 8) = *(short8*)o;
}

// ---- fused feature-gen + GEMM --------------------------------------------
// 512 threads = 8 waves, wave grid 1x8: wave w -> rows bm0..bm0+63,
// cols w*32..w*32+31 (acc[4][2]). A tile [64][128] bf16 double-buffered,
// granule XOR-swizzled by row&15 (2-way on both read & write quarters = free).
template<bool PACKED>
__global__ __launch_bounds__(512, 4) void kan_gemm(
        const float* __restrict__ x,
        const unsigned short* __restrict__ bwt,
        const float* __restrict__ ca, const float* __restrict__ cb,
        float* __restrict__ out) {
    __shared__ __align__(16) char Alds[2][16384];

    const int tid = threadIdx.x;
    const int l   = tid & 63;
    const int w   = tid >> 6;
    const int bm0 = blockIdx.x * BM;

    const int fi   = tid & 7;        // feature i-column within step
    const int frow = tid >> 3;       // feature row 0..63
    const int q = l >> 4, c = l & 15;

    f32x4 acc[4][2];
#pragma unroll
    for (int mi = 0; mi < 4; ++mi)
#pragma unroll
        for (int ni = 0; ni < 2; ++ni)
#pragma unroll
            for (int r = 0; r < 4; ++r) acc[mi][ni][r] = 0.0f;

    auto xload = [&](int s) {
        return x[(size_t)(bm0 + frow) * 256 + (size_t)(s * 8 + fi)];
    };

    auto stageA = [&](int buf, float xv) {
        float s1, c1;
        __sincosf(xv, &s1, &c1);
        alignas(16) unsigned short fc[8], fs[8];
        fc[0] = f2bf(c1); fs[0] = f2bf(s1);
        const float tc = c1 + c1;
        float cp2 = 1.0f, cp1 = c1, sp2 = 0.0f, sp1 = s1;
#pragma unroll
        for (int k = 1; k < 8; ++k) {
            float cn = tc * cp1 - cp2;
            float sn = tc * sp1 - sp2;
            cp2 = cp1; cp1 = cn; sp2 = sp1; sp1 = sn;
            fc[k] = f2bf(cn); fs[k] = f2bf(sn);
        }
        char* base = Alds[buf] + frow * 256;
        const int sw = frow & 15;
        *(short8*)(base + (((fi * 2)     ^ sw) * 16)) = *(short8*)fc;
        *(short8*)(base + (((fi * 2 + 1) ^ sw) * 16)) = *(short8*)fs;
    };

    // prologue
    float xv = xload(0);
    stageA(0, xv);
    float xn = xload(1);
    __syncthreads();

#pragma unroll 1
    for (int s = 0; s < NST; ++s) {
        const int buf = s & 1;

        // issue all B-fragment loads for this step first (hide L2 latency
        // under the feature-gen VALU work)
        short8 bfr[4][2];
#pragma unroll
        for (int ks = 0; ks < 4; ++ks) {
            const int t = s * 4 + ks;
#pragma unroll
            for (int ni = 0; ni < 2; ++ni) {
                if (PACKED) {
                    bfr[ks][ni] = *(const short8*)(
                        bwt + ((size_t)((t * 16 + w * 2 + ni) * 64 + l)) * 8);
                } else {
                    const int j = w * 32 + ni * 16 + c;
                    const int i = 2 * t + (q >> 1);
                    const float* src = ((q & 1) ? cb : ca)
                                     + ((size_t)j * 256 + i) * 8;
                    float4 v0 = ((const float4*)src)[0];
                    float4 v1 = ((const float4*)src)[1];
                    alignas(16) unsigned short o[8];
                    o[0] = f2bf(v0.x); o[1] = f2bf(v0.y);
                    o[2] = f2bf(v0.z); o[3] = f2bf(v0.w);
                    o[4] = f2bf(v1.x); o[5] = f2bf(v1.y);
                    o[6] = f2bf(v1.z); o[7] = f2bf(v1.w);
                    bfr[ks][ni] = *(short8*)o;
                }
            }
        }

        if (s + 1 < NST) stageA(buf ^ 1, xn);
        if (s + 2 < NST) xn = xload(s + 2);

#pragma unroll
        for (int ks = 0; ks < 4; ++ks) {
            short8 af[4];
#pragma unroll
            for (int mi = 0; mi < 4; ++mi) {
                const int row = mi * 16 + c;
                af[mi] = *(const short8*)(Alds[buf] + row * 256
                          + (((ks * 4 + q) ^ (row & 15)) * 16));
            }
#pragma unroll
            for (int mi = 0; mi < 4; ++mi) {
                acc[mi][0] = __builtin_amdgcn_mfma_f32_16x16x32_bf16(
                    af[mi], bfr[ks][0], acc[mi][0], 0, 0, 0);
                acc[mi][1] = __builtin_amdgcn_mfma_f32_16x16x32_bf16(
                    af[mi], bfr[ks][1], acc[mi][1], 0, 0, 0);
            }
        }
        __syncthreads();
    }

    // epilogue: frag D row = q*4+r, col = c
#pragma unroll
    for (int mi = 0; mi < 4; ++mi)
#pragma unroll
        for (int ni = 0; ni < 2; ++ni) {
            const int col = w * 32 + ni * 16 + c;
#pragma unroll
            for (int r = 0; r < 4; ++r) {
                const int row = bm0 + mi * 16 + q * 4 + r;
                out[(size_t)row * 256 + col] = acc[mi][ni][r];
            }
        }
}

extern "C" void kernel_launch(void* const* d_in, const int* in_sizes, int n_in,
                              void* d_out, int out_size, void* d_ws, size_t ws_size,
                              hipStream_t stream) {
    const float* x  = (const float*)d_in[0];
    const float* ca = (const float*)d_in[1];
    const float* cb = (const float*)d_in[2];
    float* out = (float*)d_out;

    const size_t wt_bytes = (size_t)128 * 16 * 64 * 16;   // 2 MiB

    if (ws_size >= wt_bytes) {
        unsigned short* wt = (unsigned short*)d_ws;
        pack_w_kernel<<<512, 256, 0, stream>>>(ca, cb, wt);
        kan_gemm<true><<<512, 512, 0, stream>>>(x, wt, ca, cb, out);
    } else {
        kan_gemm<false><<<512, 512, 0, stream>>>(x, nullptr, ca, cb, out);
    }
}